// Round 1
// baseline (1444.164 us; speedup 1.0000x reference)
//
#include <hip/hip_runtime.h>
#include <math.h>

// Problem constants (from reference: z (32,4096,256) f32, embed (1024,256) f32)
#define N_TOK   131072
#define DIM     256
#define K_CODE  1024
#define BT      64        // tokens per block in argmax GEMM
#define ZT_LD   260       // z-tile LDS leading dim (pad 256->260: 16B aligned, conflict-free)
#define CS_LD   20        // code-chunk LDS leading dim (pad 16->20: 16B aligned, 2-way max)
#define MARGIN  1e-3f     // top1-top2 gap below which we re-resolve in fp64

// Workspace layout (bytes)
#define WS_COUNTS   0         // 1024 * int      (histogram)
#define WS_LOSS     4096      // double          (sum of squared diffs)
#define WS_RCOUNT   4104      // int             (recheck-list count)
#define WS_INVN     8192      // 1024 * float    (1/||c_k||)
#define WS_FIDX     16384     // N_TOK * int     (final argmax index per token)
#define WS_RLIST    1048576   // N_TOK * int     (tokens needing fp64 recheck)

// Output layout (floats): z_q_st[33554432], loss, perplexity, indices[131072]
#define OUT_LOSS  33554432
#define OUT_PERP  33554433
#define OUT_IDX   33554434

// ---------------------------------------------------------------- Phase A ---
// inv_norm[k] = 1 / max(||embed_k||, eps). One wave per code.
__global__ void vq_norms(const float* __restrict__ embed, float* __restrict__ invn) {
    int lane = threadIdx.x & 63;
    int wave = (blockIdx.x * blockDim.x + threadIdx.x) >> 6;
    int nwav = (gridDim.x * blockDim.x) >> 6;
    for (int k = wave; k < K_CODE; k += nwav) {
        float4 v = *(const float4*)&embed[k * DIM + lane * 4];
        float s = v.x * v.x + v.y * v.y + v.z * v.z + v.w * v.w;
        #pragma unroll
        for (int off = 32; off; off >>= 1) s += __shfl_xor(s, off);
        if (lane == 0) invn[k] = 1.0f / fmaxf(sqrtf(s), 1e-12f);
    }
}

// ---------------------------------------------------------------- Phase B ---
// fp32 "GEMM with argmax epilogue": each block does 64 tokens x all 1024 codes.
// Thread micro-tile: 4 tokens x 8 codes. z-tile resident in LDS; code chunks
// (128 codes x 16 d) streamed through a small LDS buffer. argmax uses raw
// z . c_k * inv_norm_k  (per-token 1/||z|| is a positive scale -> argmax-invariant).
// Tracks top-2; tokens with gap < MARGIN get exact fp64 re-resolution later.
__launch_bounds__(256, 2)
__global__ void vq_argmax(const float* __restrict__ z, const float* __restrict__ embed,
                          const float* __restrict__ invn, int* __restrict__ fidx,
                          int* __restrict__ rcount, int* __restrict__ rlist) {
    __shared__ float zt[BT * ZT_LD];   // 66,560 B
    __shared__ float u0[3264];         // union: code chunk (2560 f) / reduce arrays (3264 f)

    const int tid = threadIdx.x;
    const int tx = tid & 15;           // code lane (16)
    const int ty = tid >> 4;           // token group (16)
    const int tokBase = blockIdx.x * BT;

    // Stage z tile: 64 tokens x 256 = 16384 floats, fully coalesced.
    #pragma unroll
    for (int r = 0; r < 16; ++r) {
        int flat = r * 1024 + tid * 4;
        int row = flat >> 8;
        int col = flat & 255;
        *(float4*)&zt[row * ZT_LD + col] = *(const float4*)&z[tokBase * DIM + flat];
    }
    __syncthreads();

    float best[4], second[4];
    int   bidx[4];
    #pragma unroll
    for (int i = 0; i < 4; ++i) { best[i] = -1e30f; second[i] = -1e30f; bidx[i] = 0; }

    for (int kc = 0; kc < K_CODE / 128; ++kc) {
        float acc[4][8];
        #pragma unroll
        for (int i = 0; i < 4; ++i)
            #pragma unroll
            for (int j = 0; j < 8; ++j) acc[i][j] = 0.0f;

        for (int dc = 0; dc < DIM / 16; ++dc) {
            __syncthreads();   // previous chunk's readers done
            {   // stage 128 codes x 16 d (raw embed; normalized at epilogue)
                int row  = tid >> 1;
                int half = tid & 1;
                const float* src = &embed[(kc * 128 + row) * DIM + dc * 16 + half * 8];
                float4 a = *(const float4*)src;
                float4 b = *(const float4*)(src + 4);
                *(float4*)&u0[row * CS_LD + half * 8]     = a;
                *(float4*)&u0[row * CS_LD + half * 8 + 4] = b;
            }
            __syncthreads();

            const int dbase = dc * 16;
            #pragma unroll
            for (int d4 = 0; d4 < 16; d4 += 4) {
                float4 za[4], cb[8];
                #pragma unroll
                for (int i = 0; i < 4; ++i)
                    za[i] = *(const float4*)&zt[(ty * 4 + i) * ZT_LD + dbase + d4];
                #pragma unroll
                for (int j = 0; j < 8; ++j)
                    cb[j] = *(const float4*)&u0[(tx + 16 * j) * CS_LD + d4];
                #pragma unroll
                for (int i = 0; i < 4; ++i)
                    #pragma unroll
                    for (int j = 0; j < 8; ++j)
                        acc[i][j] += za[i].x * cb[j].x + za[i].y * cb[j].y +
                                     za[i].z * cb[j].z + za[i].w * cb[j].w;
            }
        }

        // epilogue: scale by inv_norm and update per-thread top-2 (codes ascend,
        // so strict > keeps first occurrence on exact ties; tie -> second==best)
        #pragma unroll
        for (int j = 0; j < 8; ++j) {
            int code = kc * 128 + tx + 16 * j;
            float iv = invn[code];
            #pragma unroll
            for (int i = 0; i < 4; ++i) {
                float v = acc[i][j] * iv;
                if (v > best[i]) { second[i] = best[i]; best[i] = v; bidx[i] = code; }
                else             { second[i] = fmaxf(second[i], v); }
            }
        }
    }

    // Cross-thread (16 tx lanes) top-2 reduce per token via LDS.
    __syncthreads();
    float* rb = u0;                  // [64][17]
    float* rs = u0 + 1088;           // [64][17]
    int*   ri = (int*)(u0 + 2176);   // [64][17]
    #pragma unroll
    for (int i = 0; i < 4; ++i) {
        int t = ty * 4 + i;
        rb[t * 17 + tx] = best[i];
        rs[t * 17 + tx] = second[i];
        ri[t * 17 + tx] = bidx[i];
    }
    __syncthreads();
    if (tid < BT) {
        float B = -1e30f, S = -1e30f;
        int   I = 0;
        for (int x = 0; x < 16; ++x) {
            float b = rb[tid * 17 + x];
            float s = rs[tid * 17 + x];
            int  ii = ri[tid * 17 + x];
            if (b > B) { S = fmaxf(B, s); B = b; I = ii; }
            else {
                if (b == B && ii < I) I = ii;     // first-occurrence tie-break
                S = fmaxf(S, fmaxf(b, s));        // b==B -> S=B -> gap 0 -> recheck
            }
        }
        int token = tokBase + tid;
        fidx[token] = I;
        if (B - S < MARGIN) {
            int p = atomicAdd(rcount, 1);
            rlist[p] = token;
        }
    }
}

// ---------------------------------------------------------------- Phase R ---
// Exact fp64 argmax for flagged tokens (full scan of all 1024 codes).
__global__ void vq_recheck(const float* __restrict__ z, const float* __restrict__ embed,
                           const int* __restrict__ rcount, const int* __restrict__ rlist,
                           int* __restrict__ fidx) {
    __shared__ double zd[DIM];
    __shared__ double rv[256];
    __shared__ int    rix[256];
    const int cnt = *rcount;
    for (int li = blockIdx.x; li < cnt; li += gridDim.x) {
        int token = rlist[li];
        __syncthreads();
        zd[threadIdx.x] = (double)z[token * DIM + threadIdx.x];
        __syncthreads();
        double bv = -1e300;
        int    bi = 0;
        #pragma unroll
        for (int j = 0; j < 4; ++j) {
            int k = threadIdx.x * 4 + j;   // ascending per thread
            const float* e = &embed[k * DIM];
            double acc = 0.0, nrm = 0.0;
            for (int d = 0; d < DIM; d += 4) {
                float4 ef = *(const float4*)&e[d];
                acc += (double)ef.x * zd[d]     + (double)ef.y * zd[d + 1] +
                       (double)ef.z * zd[d + 2] + (double)ef.w * zd[d + 3];
                nrm += (double)ef.x * ef.x + (double)ef.y * ef.y +
                       (double)ef.z * ef.z + (double)ef.w * ef.w;
            }
            double val = acc / fmax(sqrt(nrm), 1e-12);   // 1/||z|| scale dropped
            if (val > bv) { bv = val; bi = k; }
        }
        rv[threadIdx.x]  = bv;
        rix[threadIdx.x] = bi;
        __syncthreads();
        for (int s = 128; s; s >>= 1) {
            if (threadIdx.x < s) {
                double v2 = rv[threadIdx.x + s];
                int    i2 = rix[threadIdx.x + s];
                if (v2 > rv[threadIdx.x] ||
                    (v2 == rv[threadIdx.x] && i2 < rix[threadIdx.x])) {
                    rv[threadIdx.x] = v2;
                    rix[threadIdx.x] = i2;
                }
            }
            __syncthreads();
        }
        if (threadIdx.x == 0) fidx[token] = rix[0];
    }
}

// ---------------------------------------------------------------- Phase C ---
// Gather z_q, write z_q_st = z + (z_q - z) (fp32, mimics straight-through),
// accumulate sum((z_q - z)^2) in double, histogram counts, write index floats.
// One wave per token per iteration; row of 256 f32 = 64 lanes x float4.
__global__ void vq_output(const float* __restrict__ z, const float* __restrict__ embed,
                          const int* __restrict__ fidx, float* __restrict__ out,
                          int* __restrict__ counts, double* __restrict__ lossAcc) {
    int lane = threadIdx.x & 63;
    int gw   = (blockIdx.x * blockDim.x + threadIdx.x) >> 6;
    int nwav = (gridDim.x * blockDim.x) >> 6;
    double lsum = 0.0;
    for (int t = gw; t < N_TOK; t += nwav) {
        int idx = fidx[t];
        float4 e  = *(const float4*)&embed[idx * DIM + lane * 4];
        float4 zz = *(const float4*)&z[t * DIM + lane * 4];
        float4 r, o;
        r.x = e.x - zz.x; r.y = e.y - zz.y; r.z = e.z - zz.z; r.w = e.w - zz.w;
        o.x = zz.x + r.x; o.y = zz.y + r.y; o.z = zz.z + r.z; o.w = zz.w + r.w;
        *(float4*)&out[t * DIM + lane * 4] = o;
        lsum += (double)r.x * r.x + (double)r.y * r.y +
                (double)r.z * r.z + (double)r.w * r.w;
        if (lane == 0) {
            atomicAdd(&counts[idx], 1);
            out[OUT_IDX + t] = (float)idx;
        }
    }
    #pragma unroll
    for (int off = 32; off; off >>= 1) lsum += __shfl_down(lsum, off);
    if (lane == 0) atomicAdd(lossAcc, lsum);
}

// ---------------------------------------------------------------- Phase D ---
__global__ void vq_finalize(const int* __restrict__ counts,
                            const double* __restrict__ lossAcc,
                            float* __restrict__ out) {
    __shared__ double sh[256];
    double s = 0.0;
    for (int b = threadIdx.x; b < K_CODE; b += 256) {
        double p = (double)counts[b] / (double)N_TOK;
        s += p * log(p + 1e-10);   // p==0 contributes exactly 0
    }
    sh[threadIdx.x] = s;
    __syncthreads();
    for (int st = 128; st; st >>= 1) {
        if (threadIdx.x < st) sh[threadIdx.x] += sh[threadIdx.x + st];
        __syncthreads();
    }
    if (threadIdx.x == 0) {
        out[OUT_PERP] = (float)exp(-sh[0]);
        out[OUT_LOSS] = (float)(1.25 * (*lossAcc) / (double)(N_TOK) / (double)(DIM));
    }
}

// ----------------------------------------------------------------- launch ---
extern "C" void kernel_launch(void* const* d_in, const int* in_sizes, int n_in,
                              void* d_out, int out_size, void* d_ws, size_t ws_size,
                              hipStream_t stream) {
    const float* z     = (const float*)d_in[0];
    const float* embed = (const float*)d_in[1];
    float* out = (float*)d_out;
    char*  ws  = (char*)d_ws;

    int*    counts  = (int*)   (ws + WS_COUNTS);
    double* lossAcc = (double*)(ws + WS_LOSS);
    int*    rcount  = (int*)   (ws + WS_RCOUNT);
    float*  invn    = (float*) (ws + WS_INVN);
    int*    fidx    = (int*)   (ws + WS_FIDX);
    int*    rlist   = (int*)   (ws + WS_RLIST);

    // zero counts / loss accumulator / recheck count (ws is poisoned 0xAA)
    hipMemsetAsync(ws, 0, 16384, stream);

    vq_norms  <<<16,            256, 0, stream>>>(embed, invn);
    vq_argmax <<<N_TOK / BT,    256, 0, stream>>>(z, embed, invn, fidx, rcount, rlist);
    vq_recheck<<<256,           256, 0, stream>>>(z, embed, rcount, rlist, fidx);
    vq_output <<<1024,          256, 0, stream>>>(z, embed, fidx, out, counts, lossAcc);
    vq_finalize<<<1,            256, 0, stream>>>(counts, lossAcc, out);
}

// Round 2
// 1351.969 us; speedup vs baseline: 1.0682x; 1.0682x over previous
//
#include <hip/hip_runtime.h>
#include <math.h>

// Problem constants (from reference: z (32,4096,256) f32, embed (1024,256) f32)
#define N_TOK   131072
#define DIM     256
#define K_CODE  1024
#define BT      64        // tokens per block in argmax GEMM
#define ZLD     264       // z-tile LDS leading dim in bf16 elems (256+8 pad -> 2-way max)
#define MARGIN  2e-3f     // top1-top2 gap (in ||z||-scaled units) below which we redo in fp64
                          // computation error bound ~2e-4; 10x headroom; ~0.7% of tokens flagged

// Workspace layout (bytes)
#define WS_COUNTS   0         // 1024 * int      (histogram)
#define WS_LOSS     4096      // double          (sum of squared diffs)
#define WS_RCOUNT   4104      // int             (recheck-list count)
#define WS_INVN     8192      // 1024 * float    (1/||c_k||)
#define WS_FIDX     16384     // N_TOK * int     (final argmax index per token)
#define WS_RLIST    1048576   // N_TOK * int     (tokens needing fp64 recheck)
#define WS_CH       2097152   // 1024*256 ushort (bf16 hi of codebook)
#define WS_CL       2621440   // 1024*256 ushort (bf16 lo of codebook)

// Output layout (floats): z_q_st[33554432], loss, perplexity, indices[131072]
#define OUT_LOSS  33554432
#define OUT_PERP  33554433
#define OUT_IDX   33554434

typedef __bf16 bf16x8 __attribute__((ext_vector_type(8)));
typedef float  f32x4  __attribute__((ext_vector_type(4)));

// round-to-nearest-even fp32 -> bf16 bits
static __device__ __forceinline__ unsigned short f2bf(float f) {
    unsigned int u = __float_as_uint(f);
    u += 0x7FFFu + ((u >> 16) & 1u);
    return (unsigned short)(u >> 16);
}
static __device__ __forceinline__ float bf2f(unsigned short h) {
    return __uint_as_float(((unsigned int)h) << 16);
}

// ---------------------------------------------------------------- Phase A ---
// Per code k: inv_norm[k] = 1/max(||c_k||,eps); also emit bf16 hi/lo split of
// the codebook (ch + cl). One wave per code row.
__global__ void vq_prep(const float* __restrict__ embed, float* __restrict__ invn,
                        unsigned short* __restrict__ ch, unsigned short* __restrict__ cl) {
    int lane = threadIdx.x & 63;
    int wave = (blockIdx.x * blockDim.x + threadIdx.x) >> 6;
    int nwav = (gridDim.x * blockDim.x) >> 6;
    for (int k = wave; k < K_CODE; k += nwav) {
        float4 v = *(const float4*)&embed[k * DIM + lane * 4];
        float s = v.x * v.x + v.y * v.y + v.z * v.z + v.w * v.w;
        #pragma unroll
        for (int off = 32; off; off >>= 1) s += __shfl_xor(s, off);
        if (lane == 0) invn[k] = 1.0f / fmaxf(sqrtf(s), 1e-12f);

        ushort4 hv, lv;
        hv.x = f2bf(v.x); lv.x = f2bf(v.x - bf2f(hv.x));
        hv.y = f2bf(v.y); lv.y = f2bf(v.y - bf2f(hv.y));
        hv.z = f2bf(v.z); lv.z = f2bf(v.z - bf2f(hv.z));
        hv.w = f2bf(v.w); lv.w = f2bf(v.w - bf2f(hv.w));
        *(ushort4*)&ch[k * DIM + lane * 4] = hv;
        *(ushort4*)&cl[k * DIM + lane * 4] = lv;
    }
}

// ---------------------------------------------------------------- Phase B ---
// MFMA argmax GEMM. Score = (z . c_k) * inv||c_k|| (per-token 1/||z|| scale is
// argmax-invariant). bf16 hi/lo split: zh*ch + zh*cl + zl*ch into one fp32 acc
// (dropped zl*cl ~ 2^-18 relative). Block: 64 tokens x all 1024 codes; wave w
// owns m-tile w (16 tokens); codes in 4 chunks of 256 (16 n-tiles). z staged
// once to LDS as bf16 hi/lo; B-frags load straight from the bf16 codebook
// (L1/L2 resident, all 4 waves read identical addresses). No barriers in the
// main loop. Top-2 tracked; gap < MARGIN -> exact fp64 re-resolution later.
__launch_bounds__(256, 2)
__global__ void vq_argmax(const float* __restrict__ z,
                          const unsigned short* __restrict__ ch,
                          const unsigned short* __restrict__ cl,
                          const float* __restrict__ invn, int* __restrict__ fidx,
                          int* __restrict__ rcount, int* __restrict__ rlist) {
    __shared__ unsigned short zh_s[BT * ZLD];   // 33,792 B
    __shared__ unsigned short zl_s[BT * ZLD];   // 33,792 B

    const int tid = threadIdx.x;
    const int tokBase = blockIdx.x * BT;

    // Stage + split z tile: 64 tokens x 256 f32, coalesced; one row per wave pass.
    #pragma unroll
    for (int r = 0; r < 16; ++r) {
        int flat = r * 1024 + tid * 4;
        int row = flat >> 8;
        int col = flat & 255;
        float4 v = *(const float4*)&z[tokBase * DIM + flat];
        ushort4 hv, lv;
        hv.x = f2bf(v.x); lv.x = f2bf(v.x - bf2f(hv.x));
        hv.y = f2bf(v.y); lv.y = f2bf(v.y - bf2f(hv.y));
        hv.z = f2bf(v.z); lv.z = f2bf(v.z - bf2f(hv.z));
        hv.w = f2bf(v.w); lv.w = f2bf(v.w - bf2f(hv.w));
        *(ushort4*)&zh_s[row * ZLD + col] = hv;
        *(ushort4*)&zl_s[row * ZLD + col] = lv;
    }
    __syncthreads();

    const int wave = tid >> 6;
    const int lane = tid & 63;
    const int col  = lane & 15;   // A row / D col index
    const int quad = lane >> 4;

    float best[4], second[4];
    int   bidx[4];
    #pragma unroll
    for (int r = 0; r < 4; ++r) { best[r] = -1e30f; second[r] = -1e30f; bidx[r] = 0; }

    const int aoff = (wave * 16 + col) * ZLD + quad * 8;   // ushort index
    const char* cbh = (const char*)ch;
    const char* cbl = (const char*)cl;

    for (int chunk = 0; chunk < 4; ++chunk) {
        f32x4 acc[16];
        #pragma unroll
        for (int nt = 0; nt < 16; ++nt) acc[nt] = (f32x4){0.f, 0.f, 0.f, 0.f};

        const int code0 = chunk * 256 + col;               // this lane's base code
        for (int ks = 0; ks < 8; ++ks) {
            bf16x8 ah = *(const bf16x8*)&zh_s[aoff + ks * 32];
            bf16x8 al = *(const bf16x8*)&zl_s[aoff + ks * 32];
            const char* bph = cbh + code0 * 512 + ks * 64 + quad * 16;
            const char* bpl = cbl + code0 * 512 + ks * 64 + quad * 16;
            #pragma unroll
            for (int nt = 0; nt < 16; ++nt) {
                bf16x8 bh = *(const bf16x8*)(bph + nt * 16 * 512);
                bf16x8 bl = *(const bf16x8*)(bpl + nt * 16 * 512);
                acc[nt] = __builtin_amdgcn_mfma_f32_16x16x32_bf16(ah, bh, acc[nt], 0, 0, 0);
                acc[nt] = __builtin_amdgcn_mfma_f32_16x16x32_bf16(ah, bl, acc[nt], 0, 0, 0);
                acc[nt] = __builtin_amdgcn_mfma_f32_16x16x32_bf16(al, bh, acc[nt], 0, 0, 0);
            }
        }

        // epilogue: scale by inv||c||, per-thread top-2. Codes ascend across the
        // loop for fixed col, so strict > keeps first occurrence; exact tie ->
        // second==best -> gap 0 -> recheck.
        #pragma unroll
        for (int nt = 0; nt < 16; ++nt) {
            int code = chunk * 256 + nt * 16 + col;
            float iv = invn[code];
            #pragma unroll
            for (int r = 0; r < 4; ++r) {
                float v = acc[nt][r] * iv;
                if (v > best[r]) { second[r] = best[r]; best[r] = v; bidx[r] = code; }
                else             { second[r] = fmaxf(second[r], v); }
            }
        }
    }

    // Merge top-2 across the 16 D-columns (disjoint code sets per lane).
    #pragma unroll
    for (int r = 0; r < 4; ++r) {
        #pragma unroll
        for (int off = 1; off < 16; off <<= 1) {
            float ob = __shfl_xor(best[r], off);
            float os = __shfl_xor(second[r], off);
            int   oi = __shfl_xor(bidx[r], off);
            if (ob > best[r]) {
                second[r] = fmaxf(best[r], os);
                best[r] = ob; bidx[r] = oi;
            } else {
                if (ob == best[r] && oi < bidx[r]) bidx[r] = oi;  // tie: first occurrence
                second[r] = fmaxf(second[r], ob);                 // ob==best -> gap 0 -> recheck
            }
        }
        if (col == 0) {
            int token = tokBase + wave * 16 + quad * 4 + r;   // D row = quad*4+reg
            fidx[token] = bidx[r];
            if (best[r] - second[r] < MARGIN) {
                int p = atomicAdd(rcount, 1);
                rlist[p] = token;
            }
        }
    }
}

// ---------------------------------------------------------------- Phase R ---
// Exact fp64 argmax for flagged tokens (full scan of all 1024 codes).
__global__ void vq_recheck(const float* __restrict__ z, const float* __restrict__ embed,
                           const int* __restrict__ rcount, const int* __restrict__ rlist,
                           int* __restrict__ fidx) {
    __shared__ double zd[DIM];
    __shared__ double rv[256];
    __shared__ int    rix[256];
    const int cnt = *rcount;
    for (int li = blockIdx.x; li < cnt; li += gridDim.x) {
        int token = rlist[li];
        __syncthreads();
        zd[threadIdx.x] = (double)z[token * DIM + threadIdx.x];
        __syncthreads();
        double bv = -1e300;
        int    bi = 0;
        #pragma unroll
        for (int j = 0; j < 4; ++j) {
            int k = threadIdx.x * 4 + j;   // ascending per thread
            const float* e = &embed[k * DIM];
            double acc = 0.0, nrm = 0.0;
            for (int d = 0; d < DIM; d += 4) {
                float4 ef = *(const float4*)&e[d];
                acc += (double)ef.x * zd[d]     + (double)ef.y * zd[d + 1] +
                       (double)ef.z * zd[d + 2] + (double)ef.w * zd[d + 3];
                nrm += (double)ef.x * ef.x + (double)ef.y * ef.y +
                       (double)ef.z * ef.z + (double)ef.w * ef.w;
            }
            double val = acc / fmax(sqrt(nrm), 1e-12);   // 1/||z|| scale dropped
            if (val > bv) { bv = val; bi = k; }
        }
        rv[threadIdx.x]  = bv;
        rix[threadIdx.x] = bi;
        __syncthreads();
        for (int s = 128; s; s >>= 1) {
            if (threadIdx.x < s) {
                double v2 = rv[threadIdx.x + s];
                int    i2 = rix[threadIdx.x + s];
                if (v2 > rv[threadIdx.x] ||
                    (v2 == rv[threadIdx.x] && i2 < rix[threadIdx.x])) {
                    rv[threadIdx.x] = v2;
                    rix[threadIdx.x] = i2;
                }
            }
            __syncthreads();
        }
        if (threadIdx.x == 0) fidx[token] = rix[0];
    }
}

// ---------------------------------------------------------------- Phase C ---
// Gather z_q, write z_q_st = z + (z_q - z) (fp32, mimics straight-through),
// accumulate sum((z_q - z)^2) in double, histogram counts, write index floats.
__global__ void vq_output(const float* __restrict__ z, const float* __restrict__ embed,
                          const int* __restrict__ fidx, float* __restrict__ out,
                          int* __restrict__ counts, double* __restrict__ lossAcc) {
    int lane = threadIdx.x & 63;
    int gw   = (blockIdx.x * blockDim.x + threadIdx.x) >> 6;
    int nwav = (gridDim.x * blockDim.x) >> 6;
    double lsum = 0.0;
    for (int t = gw; t < N_TOK; t += nwav) {
        int idx = fidx[t];
        float4 e  = *(const float4*)&embed[idx * DIM + lane * 4];
        float4 zz = *(const float4*)&z[t * DIM + lane * 4];
        float4 r, o;
        r.x = e.x - zz.x; r.y = e.y - zz.y; r.z = e.z - zz.z; r.w = e.w - zz.w;
        o.x = zz.x + r.x; o.y = zz.y + r.y; o.z = zz.z + r.z; o.w = zz.w + r.w;
        *(float4*)&out[t * DIM + lane * 4] = o;
        lsum += (double)r.x * r.x + (double)r.y * r.y +
                (double)r.z * r.z + (double)r.w * r.w;
        if (lane == 0) {
            atomicAdd(&counts[idx], 1);
            out[OUT_IDX + t] = (float)idx;
        }
    }
    #pragma unroll
    for (int off = 32; off; off >>= 1) lsum += __shfl_down(lsum, off);
    if (lane == 0) atomicAdd(lossAcc, lsum);
}

// ---------------------------------------------------------------- Phase D ---
__global__ void vq_finalize(const int* __restrict__ counts,
                            const double* __restrict__ lossAcc,
                            float* __restrict__ out) {
    __shared__ double sh[256];
    double s = 0.0;
    for (int b = threadIdx.x; b < K_CODE; b += 256) {
        double p = (double)counts[b] / (double)N_TOK;
        s += p * log(p + 1e-10);   // p==0 contributes exactly 0
    }
    sh[threadIdx.x] = s;
    __syncthreads();
    for (int st = 128; st; st >>= 1) {
        if (threadIdx.x < st) sh[threadIdx.x] += sh[threadIdx.x + st];
        __syncthreads();
    }
    if (threadIdx.x == 0) {
        out[OUT_PERP] = (float)exp(-sh[0]);
        out[OUT_LOSS] = (float)(1.25 * (*lossAcc) / (double)(N_TOK) / (double)(DIM));
    }
}

// ----------------------------------------------------------------- launch ---
extern "C" void kernel_launch(void* const* d_in, const int* in_sizes, int n_in,
                              void* d_out, int out_size, void* d_ws, size_t ws_size,
                              hipStream_t stream) {
    const float* z     = (const float*)d_in[0];
    const float* embed = (const float*)d_in[1];
    float* out = (float*)d_out;
    char*  ws  = (char*)d_ws;

    int*            counts  = (int*)   (ws + WS_COUNTS);
    double*         lossAcc = (double*)(ws + WS_LOSS);
    int*            rcount  = (int*)   (ws + WS_RCOUNT);
    float*          invn    = (float*) (ws + WS_INVN);
    int*            fidx    = (int*)   (ws + WS_FIDX);
    int*            rlist   = (int*)   (ws + WS_RLIST);
    unsigned short* ch      = (unsigned short*)(ws + WS_CH);
    unsigned short* cl      = (unsigned short*)(ws + WS_CL);

    // zero counts / loss accumulator / recheck count (ws is poisoned 0xAA)
    hipMemsetAsync(ws, 0, 16384, stream);

    vq_prep   <<<64,         256, 0, stream>>>(embed, invn, ch, cl);
    vq_argmax <<<N_TOK / BT, 256, 0, stream>>>(z, ch, cl, invn, fidx, rcount, rlist);
    vq_recheck<<<256,        256, 0, stream>>>(z, embed, rcount, rlist, fidx);
    vq_output <<<1024,       256, 0, stream>>>(z, embed, fidx, out, counts, lossAcc);
    vq_finalize<<<1,         256, 0, stream>>>(counts, lossAcc, out);
}

// Round 3
// 644.485 us; speedup vs baseline: 2.2408x; 2.0977x over previous
//
#include <hip/hip_runtime.h>
#include <math.h>

// Problem constants (from reference: z (32,4096,256) f32, embed (1024,256) f32)
#define N_TOK   131072
#define DIM     256
#define K_CODE  1024
#define KEXT    768       // extended K: [zh,zh,zl] x [ch,cl,ch]
#define MARGIN  2e-3f     // top1-top2 gap (||z||-scaled units) below which we redo in fp64
                          // computation error std ~3.5e-5 -> 57 sigma; flags ~0.5% of tokens

// Workspace layout (bytes)
#define WS_COUNTS   0         // 1024 * int      (histogram)
#define WS_LOSS     4096      // double          (sum of squared diffs)
#define WS_RCOUNT   4104      // int             (recheck-list count)
#define WS_INVN     8192      // 1024 * float    (1/||c_k||)
#define WS_FIDX     16384     // N_TOK * int     (final argmax index per token)
#define WS_RLIST    1048576   // N_TOK * int     (tokens needing fp64 recheck)
#define WS_BEXT     2097152   // 1024*768 bf16 = 1.5 MB packed codebook (LDS image layout)

#define CHUNK_BYTES 49152     // 32 codes x 768 x 2B, one LDS buffer

// Output layout (floats): z_q_st[33554432], loss, perplexity, indices[131072]
#define OUT_LOSS  33554432
#define OUT_PERP  33554433
#define OUT_IDX   33554434

typedef __bf16 bf16x8 __attribute__((ext_vector_type(8)));
typedef float  f32x4  __attribute__((ext_vector_type(4)));

// round-to-nearest-even fp32 -> bf16 bits
static __device__ __forceinline__ unsigned short f2bf(float f) {
    unsigned int u = __float_as_uint(f);
    u += 0x7FFFu + ((u >> 16) & 1u);
    return (unsigned short)(u >> 16);
}
static __device__ __forceinline__ float bf2f(unsigned short h) {
    return __uint_as_float(((unsigned int)h) << 16);
}

// async global->LDS, 16B per lane; LDS dest = wave-uniform base + lane*16
static __device__ __forceinline__ void load_lds16(const void* g, void* l) {
    __builtin_amdgcn_global_load_lds(
        (const __attribute__((address_space(1))) unsigned int*)g,
        (__attribute__((address_space(3))) unsigned int*)l, 16, 0, 0);
}

// ---------------------------------------------------------------- Phase A ---
// inv_norm[k] = 1/max(||c_k||,eps). One wave per code.
__global__ void vq_norms(const float* __restrict__ embed, float* __restrict__ invn) {
    int lane = threadIdx.x & 63;
    int wave = (blockIdx.x * blockDim.x + threadIdx.x) >> 6;
    int nwav = (gridDim.x * blockDim.x) >> 6;
    for (int k = wave; k < K_CODE; k += nwav) {
        float4 v = *(const float4*)&embed[k * DIM + lane * 4];
        float s = v.x * v.x + v.y * v.y + v.z * v.z + v.w * v.w;
        #pragma unroll
        for (int off = 32; off; off >>= 1) s += __shfl_xor(s, off);
        if (lane == 0) invn[k] = 1.0f / fmaxf(sqrtf(s), 1e-12f);
    }
}

// ---------------------------------------------------------------- Phase A2 --
// Pack B_ext: per code k, K-dim kk in [0,768): kk<256 -> bf16hi(c[kk]),
// kk<512 -> bf16lo(c[kk-256]), else bf16hi(c[kk-512]). Layout is the exact
// per-chunk LDS image: chunk c (32 codes) is 48 KB of
// [nt(2)][ks24(24)][quad(4)][col(16)][j(8)] bf16, so global_load_lds can
// stage it as 1 KB/wave-inst contiguous segments, and ds_read_b128 at
// lane*16 yields the MFMA B-fragment (B[n=lane&15][k=quad*8+j]) directly.
// One thread per (k, kk/8): 1024*96 = 98304 threads.
__global__ void vq_pack(const float* __restrict__ embed, unsigned short* __restrict__ bext) {
    int id = blockIdx.x * 256 + threadIdx.x;
    int k   = id / 96;
    int j8  = id - k * 96;
    int kk0 = j8 * 8;
    int src, hi;
    if (kk0 < 256)      { src = kk0;       hi = 1; }
    else if (kk0 < 512) { src = kk0 - 256; hi = 0; }
    else                { src = kk0 - 512; hi = 1; }
    const float* e = &embed[k * DIM + src];
    float4 f0 = *(const float4*)e;
    float4 f1 = *(const float4*)(e + 4);
    float v[8] = {f0.x, f0.y, f0.z, f0.w, f1.x, f1.y, f1.z, f1.w};
    unsigned short r[8] __attribute__((aligned(16)));
    #pragma unroll
    for (int j = 0; j < 8; ++j) {
        unsigned short h = f2bf(v[j]);
        r[j] = hi ? h : f2bf(v[j] - bf2f(h));
    }
    int c = k >> 5, kin = k & 31;
    int nt = kin >> 4, col = kin & 15;
    int ks = kk0 >> 5, quad = (kk0 >> 3) & 3;
    size_t dst = (size_t)c * CHUNK_BYTES + (size_t)(((nt * 24 + ks) * 64) + quad * 16 + col) * 16;
    *(float4*)((char*)bext + dst) = *(const float4*)r;
}

// ---------------------------------------------------------------- Phase B ---
// MFMA argmax GEMM, K=768 ([zh,zh,zl] . [ch,cl,ch] = zh.ch + zh.cl + zl.ch).
// Block: 128 tokens (4 waves x 2 m-tiles), all 1024 codes in 32 chunks of 32.
// A fragments live in registers (128 VGPRs, loaded once); B chunk staged to
// LDS (48 KB) via global_load_lds; each B fragment (ds_read_b128) feeds 2
// MFMAs. 2 barriers and 96 MFMAs/wave per chunk. Top-2 tracked; gap < MARGIN
// -> exact fp64 re-resolution later.
__launch_bounds__(256, 2)
__global__ void vq_argmax(const float* __restrict__ z,
                          const unsigned short* __restrict__ bext,
                          const float* __restrict__ invn, int* __restrict__ fidx,
                          int* __restrict__ rcount, int* __restrict__ rlist) {
    __shared__ unsigned short bbuf[CHUNK_BYTES / 2];   // 48 KB

    const int tid  = threadIdx.x;
    const int w    = tid >> 6;
    const int lane = tid & 63;
    const int col  = lane & 15;
    const int quad = lane >> 4;
    const int tokBase = blockIdx.x * 128;

    // ---- A fragments: wave w owns tokens [w*32, w*32+32). Per m-tile (16
    // rows): zh/zl frags for 8 k-steps of 32. A[m=lane&15][k=quad*8+j].
    bf16x8 ah[2][8], al[2][8];
    #pragma unroll
    for (int mt = 0; mt < 2; ++mt) {
        const float* zr = z + (size_t)(tokBase + w * 32 + mt * 16 + col) * DIM;
        #pragma unroll
        for (int ks = 0; ks < 8; ++ks) {
            float4 f0 = *(const float4*)(zr + ks * 32 + quad * 8);
            float4 f1 = *(const float4*)(zr + ks * 32 + quad * 8 + 4);
            float v[8] = {f0.x, f0.y, f0.z, f0.w, f1.x, f1.y, f1.z, f1.w};
            union { bf16x8 v; unsigned short u[8]; } th, tl;
            #pragma unroll
            for (int j = 0; j < 8; ++j) {
                unsigned short h = f2bf(v[j]);
                th.u[j] = h;
                tl.u[j] = f2bf(v[j] - bf2f(h));
            }
            ah[mt][ks] = th.v;
            al[mt][ks] = tl.v;
        }
    }

    float best[2][4], second[2][4];
    int   bidx[2][4];
    #pragma unroll
    for (int mt = 0; mt < 2; ++mt)
        #pragma unroll
        for (int r = 0; r < 4; ++r) { best[mt][r] = -1e30f; second[mt][r] = -1e30f; bidx[mt][r] = 0; }

    for (int c = 0; c < 32; ++c) {
        __syncthreads();   // previous chunk's readers done
        {   // stage 48 KB: wave w stages segments [w*12, w*12+12)
            const char* gsrc = (const char*)bext + (size_t)c * CHUNK_BYTES;
            #pragma unroll
            for (int i = 0; i < 12; ++i) {
                int seg = w * 12 + i;
                load_lds16(gsrc + (size_t)seg * 1024 + lane * 16,
                           (char*)bbuf + seg * 1024);
            }
        }
        __syncthreads();   // drains vmcnt (global_load_lds) via barrier semantics

        f32x4 acc[2][2];
        #pragma unroll
        for (int mt = 0; mt < 2; ++mt)
            #pragma unroll
            for (int nt = 0; nt < 2; ++nt) acc[mt][nt] = (f32x4){0.f, 0.f, 0.f, 0.f};

        #pragma unroll
        for (int nt = 0; nt < 2; ++nt) {
            const unsigned short* bb = bbuf + nt * 24 * 512;   // ushort index
            #pragma unroll
            for (int ks = 0; ks < 8; ++ks) {   // zh . ch
                bf16x8 b = *(const bf16x8*)&bb[ks * 512 + lane * 8];
                acc[0][nt] = __builtin_amdgcn_mfma_f32_16x16x32_bf16(ah[0][ks], b, acc[0][nt], 0, 0, 0);
                acc[1][nt] = __builtin_amdgcn_mfma_f32_16x16x32_bf16(ah[1][ks], b, acc[1][nt], 0, 0, 0);
            }
            #pragma unroll
            for (int ks = 0; ks < 8; ++ks) {   // zh . cl
                bf16x8 b = *(const bf16x8*)&bb[(8 + ks) * 512 + lane * 8];
                acc[0][nt] = __builtin_amdgcn_mfma_f32_16x16x32_bf16(ah[0][ks], b, acc[0][nt], 0, 0, 0);
                acc[1][nt] = __builtin_amdgcn_mfma_f32_16x16x32_bf16(ah[1][ks], b, acc[1][nt], 0, 0, 0);
            }
            #pragma unroll
            for (int ks = 0; ks < 8; ++ks) {   // zl . ch
                bf16x8 b = *(const bf16x8*)&bb[(16 + ks) * 512 + lane * 8];
                acc[0][nt] = __builtin_amdgcn_mfma_f32_16x16x32_bf16(al[0][ks], b, acc[0][nt], 0, 0, 0);
                acc[1][nt] = __builtin_amdgcn_mfma_f32_16x16x32_bf16(al[1][ks], b, acc[1][nt], 0, 0, 0);
            }
        }

        // epilogue: scale by inv||c||, per-thread top-2. Codes ascend for fixed
        // col, so strict > keeps first occurrence; exact tie -> gap 0 -> recheck.
        #pragma unroll
        for (int nt = 0; nt < 2; ++nt) {
            int code = c * 32 + nt * 16 + col;
            float iv = invn[code];
            #pragma unroll
            for (int mt = 0; mt < 2; ++mt)
                #pragma unroll
                for (int r = 0; r < 4; ++r) {
                    float v = acc[mt][nt][r] * iv;
                    if (v > best[mt][r]) { second[mt][r] = best[mt][r]; best[mt][r] = v; bidx[mt][r] = code; }
                    else                 { second[mt][r] = fmaxf(second[mt][r], v); }
                }
        }
    }

    // Merge top-2 across the 16 D-columns (disjoint code sets per lane).
    #pragma unroll
    for (int mt = 0; mt < 2; ++mt)
        #pragma unroll
        for (int r = 0; r < 4; ++r) {
            float B = best[mt][r], S = second[mt][r];
            int   I = bidx[mt][r];
            #pragma unroll
            for (int off = 1; off < 16; off <<= 1) {
                float ob = __shfl_xor(B, off);
                float os = __shfl_xor(S, off);
                int   oi = __shfl_xor(I, off);
                if (ob > B) {
                    S = fmaxf(B, os);
                    B = ob; I = oi;
                } else {
                    if (ob == B && oi < I) I = oi;   // tie: first occurrence
                    S = fmaxf(S, ob);                // ob==B -> gap 0 -> recheck
                }
            }
            if (col == 0) {
                int token = tokBase + w * 32 + mt * 16 + quad * 4 + r;   // D row = quad*4+reg
                fidx[token] = I;
                if (B - S < MARGIN) {
                    int p = atomicAdd(rcount, 1);
                    rlist[p] = token;
                }
            }
        }
}

// ---------------------------------------------------------------- Phase R ---
// Exact fp64 argmax for flagged tokens (full scan of all 1024 codes).
__global__ void vq_recheck(const float* __restrict__ z, const float* __restrict__ embed,
                           const int* __restrict__ rcount, const int* __restrict__ rlist,
                           int* __restrict__ fidx) {
    __shared__ double zd[DIM];
    __shared__ double rv[256];
    __shared__ int    rix[256];
    const int cnt = *rcount;
    for (int li = blockIdx.x; li < cnt; li += gridDim.x) {
        int token = rlist[li];
        __syncthreads();
        zd[threadIdx.x] = (double)z[token * DIM + threadIdx.x];
        __syncthreads();
        double bv = -1e300;
        int    bi = 0;
        #pragma unroll
        for (int j = 0; j < 4; ++j) {
            int k = threadIdx.x * 4 + j;   // ascending per thread
            const float* e = &embed[k * DIM];
            double acc = 0.0, nrm = 0.0;
            for (int d = 0; d < DIM; d += 4) {
                float4 ef = *(const float4*)&e[d];
                acc += (double)ef.x * zd[d]     + (double)ef.y * zd[d + 1] +
                       (double)ef.z * zd[d + 2] + (double)ef.w * zd[d + 3];
                nrm += (double)ef.x * ef.x + (double)ef.y * ef.y +
                       (double)ef.z * ef.z + (double)ef.w * ef.w;
            }
            double val = acc / fmax(sqrt(nrm), 1e-12);   // 1/||z|| scale dropped
            if (val > bv) { bv = val; bi = k; }
        }
        rv[threadIdx.x]  = bv;
        rix[threadIdx.x] = bi;
        __syncthreads();
        for (int s = 128; s; s >>= 1) {
            if (threadIdx.x < s) {
                double v2 = rv[threadIdx.x + s];
                int    i2 = rix[threadIdx.x + s];
                if (v2 > rv[threadIdx.x] ||
                    (v2 == rv[threadIdx.x] && i2 < rix[threadIdx.x])) {
                    rv[threadIdx.x] = v2;
                    rix[threadIdx.x] = i2;
                }
            }
            __syncthreads();
        }
        if (threadIdx.x == 0) fidx[token] = rix[0];
    }
}

// ---------------------------------------------------------------- Phase C ---
// Gather z_q, write z_q_st = z + (z_q - z) (fp32, mimics straight-through),
// accumulate sum((z_q - z)^2) in double, histogram counts, write index floats.
__global__ void vq_output(const float* __restrict__ z, const float* __restrict__ embed,
                          const int* __restrict__ fidx, float* __restrict__ out,
                          int* __restrict__ counts, double* __restrict__ lossAcc) {
    int lane = threadIdx.x & 63;
    int gw   = (blockIdx.x * blockDim.x + threadIdx.x) >> 6;
    int nwav = (gridDim.x * blockDim.x) >> 6;
    double lsum = 0.0;
    for (int t = gw; t < N_TOK; t += nwav) {
        int idx = fidx[t];
        float4 e  = *(const float4*)&embed[idx * DIM + lane * 4];
        float4 zz = *(const float4*)&z[(size_t)t * DIM + lane * 4];
        float4 r, o;
        r.x = e.x - zz.x; r.y = e.y - zz.y; r.z = e.z - zz.z; r.w = e.w - zz.w;
        o.x = zz.x + r.x; o.y = zz.y + r.y; o.z = zz.z + r.z; o.w = zz.w + r.w;
        *(float4*)&out[(size_t)t * DIM + lane * 4] = o;
        lsum += (double)r.x * r.x + (double)r.y * r.y +
                (double)r.z * r.z + (double)r.w * r.w;
        if (lane == 0) {
            atomicAdd(&counts[idx], 1);
            out[OUT_IDX + t] = (float)idx;
        }
    }
    #pragma unroll
    for (int off = 32; off; off >>= 1) lsum += __shfl_down(lsum, off);
    if (lane == 0) atomicAdd(lossAcc, lsum);
}

// ---------------------------------------------------------------- Phase D ---
__global__ void vq_finalize(const int* __restrict__ counts,
                            const double* __restrict__ lossAcc,
                            float* __restrict__ out) {
    __shared__ double sh[256];
    double s = 0.0;
    for (int b = threadIdx.x; b < K_CODE; b += 256) {
        double p = (double)counts[b] / (double)N_TOK;
        s += p * log(p + 1e-10);   // p==0 contributes exactly 0
    }
    sh[threadIdx.x] = s;
    __syncthreads();
    for (int st = 128; st; st >>= 1) {
        if (threadIdx.x < st) sh[threadIdx.x] += sh[threadIdx.x + st];
        __syncthreads();
    }
    if (threadIdx.x == 0) {
        out[OUT_PERP] = (float)exp(-sh[0]);
        out[OUT_LOSS] = (float)(1.25 * (*lossAcc) / (double)(N_TOK) / (double)(DIM));
    }
}

// ----------------------------------------------------------------- launch ---
extern "C" void kernel_launch(void* const* d_in, const int* in_sizes, int n_in,
                              void* d_out, int out_size, void* d_ws, size_t ws_size,
                              hipStream_t stream) {
    const float* z     = (const float*)d_in[0];
    const float* embed = (const float*)d_in[1];
    float* out = (float*)d_out;
    char*  ws  = (char*)d_ws;

    int*            counts  = (int*)   (ws + WS_COUNTS);
    double*         lossAcc = (double*)(ws + WS_LOSS);
    int*            rcount  = (int*)   (ws + WS_RCOUNT);
    float*          invn    = (float*) (ws + WS_INVN);
    int*            fidx    = (int*)   (ws + WS_FIDX);
    int*            rlist   = (int*)   (ws + WS_RLIST);
    unsigned short* bext    = (unsigned short*)(ws + WS_BEXT);

    // zero counts / loss accumulator / recheck count (ws is poisoned 0xAA)
    hipMemsetAsync(ws, 0, 16384, stream);

    vq_norms  <<<16,   256, 0, stream>>>(embed, invn);
    vq_pack   <<<384,  256, 0, stream>>>(embed, bext);
    vq_argmax <<<N_TOK / 128, 256, 0, stream>>>(z, bext, invn, fidx, rcount, rlist);
    vq_recheck<<<512,  256, 0, stream>>>(z, embed, rcount, rlist, fidx);
    vq_output <<<2048, 256, 0, stream>>>(z, embed, fidx, out, counts, lossAcc);
    vq_finalize<<<1,   256, 0, stream>>>(counts, lossAcc, out);
}